// Round 18
// baseline (344.713 us; speedup 1.0000x reference)
//
#include <hip/hip_runtime.h>
#include <math.h>

// Problem: scores = q[2048x768] @ p[16384x768]^T (fp32 in), per-query
// rank-of-target + log-softmax CE + Gaussian rank weight -> mean (scalar).
// R19: MX gemm retry with the R15 spill ROOT-CAUSED and fixed.
// R15 was numerically correct (passed, absmax 0.5) but launch_bounds(1024)
// without min-waves let the allocator target 8 waves/SIMD -> 64 VGPR ->
// total spill (WRITE 522 MB, 264 us). Fix: __launch_bounds__(1024, 1)
// (min 1 wave/EU -> regs free; 16-wave block at <=512 regs/wave always
// resident: 4 waves/SIMD x regs <= 2048 pool).
// Design: mfma_scale_f32_32x32x64_f8f6f4, unit scales (127 = x1.0 = plain
// fp8 math), BK=64 -> unit = 32 rows x 64 k-bytes (2 KB), 16 units/buf
// (8 A + 8 B) = 32 KB -> TRIPLE buffer 96 KB and 2 loads/wave/stage ->
// IDENTICAL counted-vmcnt(2) skeleton as R14 (best: 58.9 us).
// Per wave: 2x2 tiles of 32x32 (64x64 out), 4 MFMA/iter (was 32) at 2x
// rate -> MFMA work/iter 2500->~1100 cyc; LDS reads unchanged (8 b128).
// Frag: lane l = row l&31, k=(l>>5)*32+[0,32): kc=lhi*2+{0,1}, byte
// kc*512+lm32*16 (R15-verified mapping, kc 0-3). C/D 32x32: col=lane&31,
// row=(r&3)+8*(r>>2)+4*lhi (R15-verified epilogue).
// prep/merge/finalize = R18 (146.7 us total, best).
// Predict: WRITE stays ~6.1 MB (spill diagnostic!), VGPR 130-190, gemm
// ~45-50 us @R14-session clocks, MfmaUtil ~20-27 (expected drop), total
// ~132-142. Falsifier: WRITE balloons -> MX dead, R18 final; gemm flat
// -> overhead-dominated floor, stop gemm work.

#define BQ 2048
#define DD 768
#define NPASS 8
#define PP 16384
#define BM 256
#define BN 256
#define BK 64
#define KITERS 12          // 768/64
#define NBLK 64            // PP/BN
#define MBLK 8             // BQ/BM
#define NCHUNKS 256        // NBLK * 4 n-waves

#define ALPHA_C 2.6f
#define INV_2SIG2 (1.0f/6.48f)   // 1/(2*1.8^2)

typedef __attribute__((ext_vector_type(16))) float floatx16; // 32x32 C/D
typedef __attribute__((ext_vector_type(4))) int intx4;       // ds_read_b128
typedef __attribute__((ext_vector_type(8))) int intx8;       // MFMA A/B

// ---------------------------------------------------------------------------
// Kernel 1 (fused): cast q,p -> fp8 e4m3 (16 floats/thread, uint4 stores)
// + s_t exact-fp32 dots + out=0.  (R18, unchanged)
// ---------------------------------------------------------------------------
#define NQ16   98304     // 2048*768/16
#define NTOT16 884736    // (2048+16384)*768/16
#define NCB16  3456      // NTOT16/256
__global__ __launch_bounds__(256) void prep_kernel(const float* __restrict__ qf,
                                                   const float* __restrict__ pf,
                                                   uint4* __restrict__ qb,
                                                   uint4* __restrict__ pb,
                                                   float* __restrict__ st,
                                                   float* __restrict__ out) {
  const int b = blockIdx.x;
  if (b == 0 && threadIdx.x == 0) *out = 0.f;
  if (b < NCB16) {
    const int i = b * 256 + threadIdx.x;        // 16-float unit index
    const float4* src; uint4* dst;
    if (i < NQ16) { src = (const float4*)qf + 4 * (size_t)i; dst = qb + i; }
    else { const size_t j = (size_t)i - NQ16; src = (const float4*)pf + 4 * j; dst = pb + j; }
    const float4 v0 = src[0], v1 = src[1], v2 = src[2], v3 = src[3];
    unsigned u0 = __builtin_amdgcn_cvt_pk_fp8_f32(v0.x, v0.y, 0, 0);
    u0 = __builtin_amdgcn_cvt_pk_fp8_f32(v0.z, v0.w, u0, 1);
    unsigned u1 = __builtin_amdgcn_cvt_pk_fp8_f32(v1.x, v1.y, 0, 0);
    u1 = __builtin_amdgcn_cvt_pk_fp8_f32(v1.z, v1.w, u1, 1);
    unsigned u2 = __builtin_amdgcn_cvt_pk_fp8_f32(v2.x, v2.y, 0, 0);
    u2 = __builtin_amdgcn_cvt_pk_fp8_f32(v2.z, v2.w, u2, 1);
    unsigned u3 = __builtin_amdgcn_cvt_pk_fp8_f32(v3.x, v3.y, 0, 0);
    u3 = __builtin_amdgcn_cvt_pk_fp8_f32(v3.z, v3.w, u3, 1);
    uint4 w; w.x = u0; w.y = u1; w.z = u2; w.w = u3;
    *dst = w;
  } else {
    const int wv = threadIdx.x >> 6, lane = threadIdx.x & 63;
    const int qi = (b - NCB16) * 4 + wv;
    const float4* q4 = (const float4*)(qf + (size_t)qi * DD);
    const float4* p4 = (const float4*)(pf + (size_t)qi * NPASS * DD);
    float acc = 0.f;
#pragma unroll
    for (int u = 0; u < 3; ++u) {   // 192 float4 per row = 64 lanes * 3
      float4 a = q4[lane + 64 * u];
      float4 c = p4[lane + 64 * u];
      acc = fmaf(a.x, c.x, acc);
      acc = fmaf(a.y, c.y, acc);
      acc = fmaf(a.z, c.z, acc);
      acc = fmaf(a.w, c.w, acc);
    }
#pragma unroll
    for (int off = 32; off >= 1; off >>= 1) acc += __shfl_xor(acc, off);
    if (lane == 0) st[qi] = acc;
  }
}

// ---------------------------------------------------------------------------
// Kernel 2: MX-scaled fp8 GEMM 256x256, BK=64, triple-buffered, counted
// vmcnt(2) — R14 sync skeleton with 32x32x64 f8f6f4 MFMAs (unit scales).
// 16 waves (4m x 4n), wave = 64x64 out = 2x2 tiles of 32x32.
// A unit u (u=0..7): rows qbase+u*32; B unit u: rows n0+u*32. Unit = 2 KB,
// [kc(4)][row(32)][16B]. Wave wv stages A unit wv (wv<8) / B unit wv-8.
// ---------------------------------------------------------------------------
__global__ __launch_bounds__(1024, 1) void gemm_kernel(const unsigned char* __restrict__ qb,
                                                       const unsigned char* __restrict__ pb,
                                                       const float* __restrict__ st,
                                                       float* __restrict__ pm,
                                                       float* __restrict__ pl,
                                                       float* __restrict__ pc) {
  __shared__ unsigned char As[3][8 * 2048];    // 48 KB
  __shared__ unsigned char Bs[3][8 * 2048];    // 48 KB
  __shared__ float st_lds[BM];

  const int t = threadIdx.x;
  const int lane = t & 63;
  const int wv = t >> 6;            // 0..15
  const int wm = wv >> 2, wn = wv & 3;
  const int bid = blockIdx.x;       // 0..511
  const int xcd = bid & 7;          // round-robin XCD assignment
  const int nb = xcd * 8 + ((bid >> 3) & 7);   // XCD-private pb slice (1.5 MB)
  const int mb = bid >> 6;          // 0..7
  const int qbase = mb * BM;
  const int n0 = nb * BN;
  const int lm32 = lane & 31;
  const int lhi = lane >> 5;

  if (t < BM) st_lds[t] = st[qbase + t];

  floatx16 acc[2][2];
#pragma unroll
  for (int i = 0; i < 2; ++i)
#pragma unroll
    for (int j = 0; j < 2; ++j)
#pragma unroll
      for (int r = 0; r < 16; ++r) acc[i][j][r] = 0.f;

  // staging role: wave wv owns A unit wv (wv<8) or B unit wv-8
  const int srow = (wv < 8) ? (qbase + wv * 32) : (n0 + (wv - 8) * 32);
  const unsigned char* const sbase =
      ((wv < 8) ? qb : pb) + (size_t)(srow + lm32) * DD;

  // stage(kt, buf): 2 x global_load_lds of 1 KB. LDS byte v*1024 + lane*16
  // decodes to kc = 2v+(lane>>5), row = lane&31; matching global k-offset
  // kt*64 + (2v+lhi)*16 at row srow+lm32.
#define STAGE(KT, BUF)                                                          \
  {                                                                             \
    __attribute__((address_space(3))) unsigned char* ldst =                     \
        (__attribute__((address_space(3))) unsigned char*)                      \
        ((wv < 8) ? &As[BUF][wv * 2048] : &Bs[BUF][(wv - 8) * 2048]);           \
    _Pragma("unroll")                                                           \
    for (int v = 0; v < 2; ++v) {                                               \
      __builtin_amdgcn_global_load_lds(                                         \
          (const __attribute__((address_space(1))) void*)(sbase + (size_t)(KT) * BK + (2 * v + lhi) * 16), \
          (__attribute__((address_space(3))) void*)(ldst + v * 1024 + lane * 16), \
          16, 0, 0);                                                            \
    }                                                                           \
  }

  // frag: lane l -> row l&31, k = (l>>5)*32+[0,32): kc = lhi*2 + {0,1};
  // two b128 at byte lhi*1024 + lm32*16 and +512, concatenated to v8i32.
#define FRAG(dst, ARR, CBUF, UNIT)                                              \
  {                                                                             \
    const unsigned char* ub = &ARR[CBUF][(UNIT) * 2048] + lhi * 1024 + lm32 * 16; \
    intx4 lo = *(const intx4*)ub;                                               \
    intx4 hi = *(const intx4*)(ub + 512);                                       \
    dst = __builtin_shufflevector(lo, hi, 0, 1, 2, 3, 4, 5, 6, 7);              \
  }

  // 8 ds_read_b128 + 4 scaled MFMAs (scale 127 -> x1.0 = plain fp8 math)
#define COMPUTE(CB)                                                             \
  {                                                                             \
    intx8 af[2], bf[2];                                                         \
    FRAG(af[0], As, CB, wm * 2 + 0)                                             \
    FRAG(af[1], As, CB, wm * 2 + 1)                                             \
    FRAG(bf[0], Bs, CB, wn * 2 + 0)                                             \
    FRAG(bf[1], Bs, CB, wn * 2 + 1)                                             \
    __builtin_amdgcn_s_setprio(1);                                              \
    acc[0][0] = __builtin_amdgcn_mfma_scale_f32_32x32x64_f8f6f4(af[0], bf[0], acc[0][0], 0, 0, 0, 127, 0, 127); \
    acc[0][1] = __builtin_amdgcn_mfma_scale_f32_32x32x64_f8f6f4(af[0], bf[1], acc[0][1], 0, 0, 0, 127, 0, 127); \
    acc[1][0] = __builtin_amdgcn_mfma_scale_f32_32x32x64_f8f6f4(af[1], bf[0], acc[1][0], 0, 0, 0, 127, 0, 127); \
    acc[1][1] = __builtin_amdgcn_mfma_scale_f32_32x32x64_f8f6f4(af[1], bf[1], acc[1][1], 0, 0, 0, 127, 0, 127); \
    __builtin_amdgcn_s_setprio(0);                                              \
  }

  STAGE(0, 0)
  STAGE(1, 1)
  int cur = 0;            // buffer holding K-tile kt
  int stg = 2;            // buffer to stage K-tile kt+2 into
  for (int kt = 0; kt < KITERS - 1; ++kt) {
    // own stage-kt's 2 loads done (2 newest = stage kt+1 may stay in flight)
    asm volatile("s_waitcnt vmcnt(2)" ::: "memory");
    __builtin_amdgcn_s_barrier();          // all waves: stage kt complete,
    __builtin_amdgcn_sched_barrier(0);     // and all past iter kt-1 reads
    if (kt < KITERS - 2) STAGE(kt + 2, stg)
    COMPUTE(cur)
    cur = (cur == 2) ? 0 : cur + 1;
    stg = (stg == 2) ? 0 : stg + 1;
  }
  // peeled final iteration: drain the last stage
  asm volatile("s_waitcnt vmcnt(0)" ::: "memory");
  __builtin_amdgcn_s_barrier();
  __builtin_amdgcn_sched_barrier(0);
  COMPUTE(cur)

  // ---- fused epilogue (R15-verified): per-row max / sumexp / count ----
  // C/D 32x32: col = lane&31, row = (r&3)+8*(r>>2)+4*lhi. Chunk-major
  // partials: chunk = nb*4+wn owns cols n0+wn*64..+63.
  const int chunk = nb * 4 + wn;
  float* const pmc = pm + (size_t)chunk * BQ;
  float* const plc = pl + (size_t)chunk * BQ;
  float* const pcc = pc + (size_t)chunk * BQ;
  const int cgbase = n0 + wn * 64 + lm32;
#pragma unroll
  for (int i = 0; i < 2; ++i) {
#pragma unroll
    for (int r = 0; r < 16; ++r) {
      const int rl = wm * 64 + i * 32 + (r & 3) + 8 * (r >> 2) + 4 * lhi;
      const float s0 = acc[i][0][r], s1 = acc[i][1][r];
      float mx = fmaxf(s0, s1);
#pragma unroll
      for (int off = 1; off <= 16; off <<= 1) mx = fmaxf(mx, __shfl_xor(mx, off));
      const float stv = st_lds[rl];
      const int qg = qbase + rl;
      const int tcol = qg * NPASS;
      float sum = __expf(s0 - mx) + __expf(s1 - mx);
      float c = 0.f;
      if (s0 > stv && cgbase != tcol) c += 1.f;
      if (s1 > stv && cgbase + 32 != tcol) c += 1.f;
#pragma unroll
      for (int off = 1; off <= 16; off <<= 1) {
        sum += __shfl_xor(sum, off);
        c += __shfl_xor(c, off);
      }
      if (lm32 == 0) {
        pmc[qg] = mx; plc[qg] = sum; pcc[qg] = c;
      }
    }
  }
}

// ---------------------------------------------------------------------------
// Kernel 3a (stage A): merge chunks 32-at-a-time. (R18, unchanged)
// ---------------------------------------------------------------------------
__global__ __launch_bounds__(256) void merge_kernel(const float* __restrict__ pm,
                                                    const float* __restrict__ pl,
                                                    const float* __restrict__ pc,
                                                    float* __restrict__ pm2,
                                                    float* __restrict__ pl2,
                                                    float* __restrict__ pc2) {
  const int wv = threadIdx.x >> 6, lane = threadIdx.x & 63;
  const int q = (blockIdx.x & 31) * 64 + lane;
  const int slice = blockIdx.x >> 5;
  const int c0 = slice * 32 + wv * 8;
  float m = -1e30f, l = 0.f, c = 0.f;
#pragma unroll
  for (int ch = 0; ch < 8; ++ch) {
    const size_t idx = (size_t)(c0 + ch) * BQ + q;
    const float mv = pm[idx], lv = pl[idx], cv = pc[idx];
    const float nm = fmaxf(m, mv);
    l = l * __expf(m - nm) + lv * __expf(mv - nm);
    m = nm; c += cv;
  }
  __shared__ float sm[4][64], sl[4][64], sc[4][64];
  sm[wv][lane] = m; sl[wv][lane] = l; sc[wv][lane] = c;
  __syncthreads();
  if (wv == 0) {
    float M = sm[0][lane], L = sl[0][lane], C = sc[0][lane];
#pragma unroll
    for (int w = 1; w < 4; ++w) {
      const float mv = sm[w][lane];
      const float nm = fmaxf(M, mv);
      L = L * __expf(M - nm) + sl[w][lane] * __expf(mv - nm);
      M = nm; C += sc[w][lane];
    }
    const size_t o = (size_t)slice * BQ + q;
    pm2[o] = M; pl2[o] = L; pc2[o] = C;
  }
}

// ---------------------------------------------------------------------------
// Kernel 3b (stage B): merge 8 slices/query, weighted CE, mean. (R18)
// ---------------------------------------------------------------------------
__global__ __launch_bounds__(64) void finalize_kernel(const float* __restrict__ st,
                                                      const float* __restrict__ pm2,
                                                      const float* __restrict__ pl2,
                                                      const float* __restrict__ pc2,
                                                      float* __restrict__ out) {
  const int lane = threadIdx.x;
  const int q = blockIdx.x * 64 + lane;
  float m = -1e30f, l = 0.f, c = 0.f;
#pragma unroll
  for (int s = 0; s < 8; ++s) {
    const size_t idx = (size_t)s * BQ + q;
    const float mv = pm2[idx], lv = pl2[idx], cv = pc2[idx];
    const float nm = fmaxf(m, mv);
    l = l * __expf(m - nm) + lv * __expf(mv - nm);
    m = nm; c += cv;
  }
  const float raw = logf(l) + m - st[q];       // -log_softmax[target]
  const float dr = c - 1.0f;                   // rank - OPTIMAL_RANK
  const float w = 1.0f + ALPHA_C * __expf(-(dr * dr) * INV_2SIG2);
  float loss = raw * w * (1.0f / (float)BQ);
#pragma unroll
  for (int off = 32; off >= 1; off >>= 1) loss += __shfl_xor(loss, off);
  if (lane == 0) atomicAdd(out, loss);
}

// ---------------------------------------------------------------------------
extern "C" void kernel_launch(void* const* d_in, const int* in_sizes, int n_in,
                              void* d_out, int out_size, void* d_ws, size_t ws_size,
                              hipStream_t stream) {
  const float* q = (const float*)d_in[0];
  const float* p = (const float*)d_in[1];
  char* ws = (char*)d_ws;
  unsigned char* qb = (unsigned char*)ws;                  // 1,572,864 B
  unsigned char* pb = (unsigned char*)(ws + 1572864);      // 12,582,912 B
  float* st = (float*)(ws + 14155776);                     // 8 KB
  float* pm = (float*)(ws + 14163968);                     // 2 MB
  float* pl = (float*)(ws + 16261120);                     // 2 MB
  float* pc = (float*)(ws + 18358272);                     // 2 MB
  float* pm2 = (float*)(ws + 20455424);                    // 64 KB
  float* pl2 = (float*)(ws + 20520960);                    // 64 KB
  float* pc2 = (float*)(ws + 20586496);                    // 64 KB (end ~20.7 MB)
  float* out = (float*)d_out;

  prep_kernel<<<NCB16 + BQ / 4, 256, 0, stream>>>(q, p, (uint4*)qb, (uint4*)pb, st, out);
  gemm_kernel<<<NBLK * MBLK, 1024, 0, stream>>>(qb, pb, st, pm, pl, pc);
  merge_kernel<<<256, 256, 0, stream>>>(pm, pl, pc, pm2, pl2, pc2);
  finalize_kernel<<<BQ / 64, 64, 0, stream>>>(st, pm2, pl2, pc2, out);
}

// Round 19
// 182.308 us; speedup vs baseline: 1.8908x; 1.8908x over previous
//
#include <hip/hip_runtime.h>
#include <math.h>

// Problem: scores = q[2048x768] @ p[16384x768]^T (fp32 in), per-query
// rank-of-target + log-softmax CE + Gaussian rank weight -> mean (scalar).
// R20: fuse the pb fp32->fp8 cast INTO gemm's B staging (kill the
// prep->gemm serialization). R19 post-mortem: MX spilled again (WRITE
// 488 MB, VGPR pinned 64) despite launch_bounds(1024,1) -> MX closed per
// falsifier; 16x16 fp8 R14 skeleton is the gemm.
// Non-gemm ~85 us (prep 70MB traffic + serialization); gemm has 3-4x
// slack on every pipe (33%). So:
//  - gemm B units reg-staged from pf fp32 directly: each lane reads ONE
//    64B-aligned line (4xfloat4), cvt_pk (identical fp8 bytes as prep
//    made), 2x ds_write_b64 to the IDENTICAL LDS layout. A keeps
//    global_load_lds from qb. Queue order B-loads->A-gld: compiler
//    auto-waits B regs in-stage; manual top-of-iter wait = vmcnt(1)
//    (A(kt) oldest outstanding) + lgkmcnt(0) (ds_writes flushed before
//    barrier -> visible 2 barriers before their read). Two-half B
//    processing + sched_barrier caps transient VGPRs (~+8).
//  - prep: q-cast (384 blocks, 6MB) + st-dots only. pb buffer unused.
//  - merge/finalize = R18.
// Scores bit-identical -> absmax 0.5. Predict: gemm 62-75, FETCH ~60MB
// (pf first-touch), WRITE ~6MB (SPILL DIAGNOSTIC), total ~125-140.
// Falsifiers (either -> declare R18 final): WRITE >> 10MB = spill;
// gemm > 85 = L3 BW / staging serialization.

#define BQ 2048
#define DD 768
#define NPASS 8
#define PP 16384
#define BM 256
#define BN 256
#define BK 64
#define KITERS 12          // 768/64
#define NBLK 64            // PP/BN
#define MBLK 8             // BQ/BM
#define NCHUNKS 256        // NBLK * 4 n-waves

#define ALPHA_C 2.6f
#define INV_2SIG2 (1.0f/6.48f)   // 1/(2*1.8^2)

typedef __attribute__((ext_vector_type(4))) float floatx4;  // MFMA C/D
typedef __attribute__((ext_vector_type(2))) long longx2;    // ds_read_b128

// ---------------------------------------------------------------------------
// Kernel 1: cast q -> fp8 e4m3 (16 floats/thread) + s_t exact dots + out=0.
// (pb cast REMOVED — done inside gemm now.)
// ---------------------------------------------------------------------------
#define QCB 384          // 2048*768/16/256
__global__ __launch_bounds__(256) void prep_kernel(const float* __restrict__ qf,
                                                   const float* __restrict__ pf,
                                                   uint4* __restrict__ qb,
                                                   float* __restrict__ st,
                                                   float* __restrict__ out) {
  const int b = blockIdx.x;
  if (b == 0 && threadIdx.x == 0) *out = 0.f;
  if (b < QCB) {
    const int i = b * 256 + threadIdx.x;        // 16-float unit index
    const float4* src = (const float4*)qf + 4 * (size_t)i;
    const float4 v0 = src[0], v1 = src[1], v2 = src[2], v3 = src[3];
    unsigned u0 = __builtin_amdgcn_cvt_pk_fp8_f32(v0.x, v0.y, 0, 0);
    u0 = __builtin_amdgcn_cvt_pk_fp8_f32(v0.z, v0.w, u0, 1);
    unsigned u1 = __builtin_amdgcn_cvt_pk_fp8_f32(v1.x, v1.y, 0, 0);
    u1 = __builtin_amdgcn_cvt_pk_fp8_f32(v1.z, v1.w, u1, 1);
    unsigned u2 = __builtin_amdgcn_cvt_pk_fp8_f32(v2.x, v2.y, 0, 0);
    u2 = __builtin_amdgcn_cvt_pk_fp8_f32(v2.z, v2.w, u2, 1);
    unsigned u3 = __builtin_amdgcn_cvt_pk_fp8_f32(v3.x, v3.y, 0, 0);
    u3 = __builtin_amdgcn_cvt_pk_fp8_f32(v3.z, v3.w, u3, 1);
    uint4 w; w.x = u0; w.y = u1; w.z = u2; w.w = u3;
    qb[i] = w;
  } else {
    const int wv = threadIdx.x >> 6, lane = threadIdx.x & 63;
    const int qi = (b - QCB) * 4 + wv;
    const float4* q4 = (const float4*)(qf + (size_t)qi * DD);
    const float4* p4 = (const float4*)(pf + (size_t)qi * NPASS * DD);
    float acc = 0.f;
#pragma unroll
    for (int u = 0; u < 3; ++u) {   // 192 float4 per row = 64 lanes * 3
      float4 a = q4[lane + 64 * u];
      float4 c = p4[lane + 64 * u];
      acc = fmaf(a.x, c.x, acc);
      acc = fmaf(a.y, c.y, acc);
      acc = fmaf(a.z, c.z, acc);
      acc = fmaf(a.w, c.w, acc);
    }
#pragma unroll
    for (int off = 32; off >= 1; off >>= 1) acc += __shfl_xor(acc, off);
    if (lane == 0) st[qi] = acc;
  }
}

// ---------------------------------------------------------------------------
// Kernel 2: fp8 MFMA GEMM 256x256, BK=64, triple-buffered, counted vmcnt
// (R14 skeleton). A staged via global_load_lds from qb (fp8). B staged from
// pf (fp32) in-register: lane (lm,lq) owns row n0+wv*16+lm, elements
// kt*64+lq*16..+16 = one 64B line; cvt_pk -> same fp8 bytes as old prep;
// 2x ds_write_b64 to byte wv*1024 + lane*16 (+8) = the layout gload_lds
// produced. Frag reads (R13 conflict-free b128 K-permuted) unchanged.
// C/D: col=lane&15, row=(lane>>4)*4+reg. Chunk-major partials (R11).
// Waits: top-of-iter "vmcnt(1) lgkmcnt(0)" — B-reg loads are auto-waited
// by the compiler inside their own STAGE, so outstanding VMEM at top of
// iter kt = {A(kt), A(kt+1)}; vmcnt(1) waits A(kt). lgkmcnt(0) flushes
// iter kt-1's ds_writes before the barrier (read 1+ barrier later).
// ---------------------------------------------------------------------------
__global__ __launch_bounds__(1024) void gemm_kernel(const unsigned char* __restrict__ qb,
                                                    const float* __restrict__ pf,
                                                    const float* __restrict__ st,
                                                    float* __restrict__ pm,
                                                    float* __restrict__ pl,
                                                    float* __restrict__ pc) {
  __shared__ unsigned char As[3][16 * 1024];   // 48 KB
  __shared__ unsigned char Bs[3][16 * 1024];   // 48 KB
  __shared__ float st_lds[BM];

  const int t = threadIdx.x;
  const int lane = t & 63;
  const int wv = t >> 6;            // 0..15
  const int wm = wv >> 2, wn = wv & 3;
  const int bid = blockIdx.x;       // 0..511
  const int xcd = bid & 7;          // round-robin XCD assignment
  const int nb = xcd * 8 + ((bid >> 3) & 7);   // XCD-private pf slice
  const int mb = bid >> 6;          // 0..7
  const int qbase = mb * BM;
  const int n0 = nb * BN;
  const int lm = lane & 15;
  const int lq = lane >> 4;
  const int lds_lane = lane * 16;

  if (t < BM) st_lds[t] = st[qbase + t];

  floatx4 acc[4][4];
#pragma unroll
  for (int i = 0; i < 4; ++i)
#pragma unroll
    for (int j = 0; j < 4; ++j) acc[i][j] = (floatx4){0.f, 0.f, 0.f, 0.f};

  const size_t arow = (size_t)(qbase + wv * 16 + lm) * DD;
  const float* const brow = pf + (size_t)(n0 + wv * 16 + lm) * DD;
  const int intra16 = lq * 256 + lm * 16;      // one 16-B chunk per lane

  // stage(kt, buf): B fp32 reg-stage (two halves, capped transients) + A
  // gload_lds. B loads first, A last -> compiler's in-stage wait for B regs
  // is counted (leaves A in flight).
#define STAGE(KT, BUF)                                                          \
  {                                                                             \
    const float4* bsrc = (const float4*)(brow + (size_t)(KT) * BK + lq * 16);   \
    const float4 f0 = bsrc[0], f1 = bsrc[1];                                    \
    __builtin_amdgcn_global_load_lds(                                           \
        (const __attribute__((address_space(1))) void*)(qb + arow + (size_t)(KT) * BK + lq * 16), \
        (__attribute__((address_space(3))) void*)(&As[BUF][wv * 1024] + lds_lane), \
        16, 0, 0);                                                              \
    unsigned u0 = __builtin_amdgcn_cvt_pk_fp8_f32(f0.x, f0.y, 0, 0);            \
    u0 = __builtin_amdgcn_cvt_pk_fp8_f32(f0.z, f0.w, u0, 1);                    \
    unsigned u1 = __builtin_amdgcn_cvt_pk_fp8_f32(f1.x, f1.y, 0, 0);            \
    u1 = __builtin_amdgcn_cvt_pk_fp8_f32(f1.z, f1.w, u1, 1);                    \
    uint2 w0; w0.x = u0; w0.y = u1;                                             \
    *reinterpret_cast<uint2*>(&Bs[BUF][wv * 1024] + lds_lane) = w0;             \
    __builtin_amdgcn_sched_barrier(0);                                          \
    const float4 f2 = bsrc[2], f3 = bsrc[3];                                    \
    unsigned u2 = __builtin_amdgcn_cvt_pk_fp8_f32(f2.x, f2.y, 0, 0);            \
    u2 = __builtin_amdgcn_cvt_pk_fp8_f32(f2.z, f2.w, u2, 1);                    \
    unsigned u3 = __builtin_amdgcn_cvt_pk_fp8_f32(f3.x, f3.y, 0, 0);            \
    u3 = __builtin_amdgcn_cvt_pk_fp8_f32(f3.z, f3.w, u3, 1);                    \
    uint2 w1; w1.x = u2; w1.y = u3;                                             \
    *reinterpret_cast<uint2*>(&Bs[BUF][wv * 1024] + lds_lane + 8) = w1;         \
  }

#define MFMA8(II, JJ)                                                           \
  {                                                                             \
    acc[II][JJ]       = __builtin_amdgcn_mfma_f32_16x16x32_fp8_fp8(a2[II].x,     b2[JJ].x,     acc[II][JJ],       0, 0, 0); \
    acc[II][JJ+1]     = __builtin_amdgcn_mfma_f32_16x16x32_fp8_fp8(a2[II].x,     b2[JJ+1].x,   acc[II][JJ+1],     0, 0, 0); \
    acc[II+1][JJ]     = __builtin_amdgcn_mfma_f32_16x16x32_fp8_fp8(a2[II+1].x,   b2[JJ].x,     acc[II+1][JJ],     0, 0, 0); \
    acc[II+1][JJ+1]   = __builtin_amdgcn_mfma_f32_16x16x32_fp8_fp8(a2[II+1].x,   b2[JJ+1].x,   acc[II+1][JJ+1],   0, 0, 0); \
    acc[II][JJ]       = __builtin_amdgcn_mfma_f32_16x16x32_fp8_fp8(a2[II].y,     b2[JJ].y,     acc[II][JJ],       0, 0, 0); \
    acc[II][JJ+1]     = __builtin_amdgcn_mfma_f32_16x16x32_fp8_fp8(a2[II].y,     b2[JJ+1].y,   acc[II][JJ+1],     0, 0, 0); \
    acc[II+1][JJ]     = __builtin_amdgcn_mfma_f32_16x16x32_fp8_fp8(a2[II+1].y,   b2[JJ].y,     acc[II+1][JJ],     0, 0, 0); \
    acc[II+1][JJ+1]   = __builtin_amdgcn_mfma_f32_16x16x32_fp8_fp8(a2[II+1].y,   b2[JJ+1].y,   acc[II+1][JJ+1],   0, 0, 0); \
  }

#define COMPUTE(CB)                                                             \
  {                                                                             \
    longx2 a2[4], b2[4];                                                        \
    a2[0] = *(const longx2*)(&As[CB][(wm * 4 + 0) * 1024] + intra16);           \
    a2[1] = *(const longx2*)(&As[CB][(wm * 4 + 1) * 1024] + intra16);           \
    b2[0] = *(const longx2*)(&Bs[CB][(wn * 4 + 0) * 1024] + intra16);           \
    b2[1] = *(const longx2*)(&Bs[CB][(wn * 4 + 1) * 1024] + intra16);           \
    __builtin_amdgcn_sched_barrier(0);                                          \
    b2[2] = *(const longx2*)(&Bs[CB][(wn * 4 + 2) * 1024] + intra16);           \
    b2[3] = *(const longx2*)(&Bs[CB][(wn * 4 + 3) * 1024] + intra16);           \
    __builtin_amdgcn_sched_barrier(0);                                          \
    __builtin_amdgcn_s_setprio(1);                                              \
    MFMA8(0, 0)                                                                 \
    __builtin_amdgcn_s_setprio(0);                                              \
    __builtin_amdgcn_sched_barrier(0);                                          \
    a2[2] = *(const longx2*)(&As[CB][(wm * 4 + 2) * 1024] + intra16);           \
    a2[3] = *(const longx2*)(&As[CB][(wm * 4 + 3) * 1024] + intra16);           \
    __builtin_amdgcn_sched_barrier(0);                                          \
    __builtin_amdgcn_s_setprio(1);                                              \
    MFMA8(0, 2)                                                                 \
    __builtin_amdgcn_s_setprio(0);                                              \
    __builtin_amdgcn_sched_barrier(0);                                          \
    __builtin_amdgcn_s_setprio(1);                                              \
    MFMA8(2, 0)                                                                 \
    MFMA8(2, 2)                                                                 \
    __builtin_amdgcn_s_setprio(0);                                              \
  }

  STAGE(0, 0)
  STAGE(1, 1)
  int cur = 0;            // buffer holding K-tile kt
  int stg = 2;            // buffer to stage K-tile kt+2 into
  for (int kt = 0; kt < KITERS - 1; ++kt) {
    // A(kt) = oldest outstanding VMEM (B regs auto-waited in-stage);
    // lgkmcnt(0) flushes iter kt-1's ds_writes before the barrier.
    asm volatile("s_waitcnt vmcnt(1) lgkmcnt(0)" ::: "memory");
    __builtin_amdgcn_s_barrier();
    __builtin_amdgcn_sched_barrier(0);
    if (kt < KITERS - 2) STAGE(kt + 2, stg)
    COMPUTE(cur)
    cur = (cur == 2) ? 0 : cur + 1;
    stg = (stg == 2) ? 0 : stg + 1;
  }
  // peeled final iteration: drain everything
  asm volatile("s_waitcnt vmcnt(0) lgkmcnt(0)" ::: "memory");
  __builtin_amdgcn_s_barrier();
  __builtin_amdgcn_sched_barrier(0);
  COMPUTE(cur)

  // ---- fused epilogue: chunk-major partials (proven R11) ----
  const int chunk = nb * 4 + wn;
  float* const pmc = pm + (size_t)chunk * BQ;
  float* const plc = pl + (size_t)chunk * BQ;
  float* const pcc = pc + (size_t)chunk * BQ;
#pragma unroll
  for (int i = 0; i < 4; ++i) {
#pragma unroll
    for (int r = 0; r < 4; ++r) {
      const int rl = wm * 64 + i * 16 + lq * 4 + r;   // local query row
      float mx = fmaxf(fmaxf(acc[i][0][r], acc[i][1][r]),
                       fmaxf(acc[i][2][r], acc[i][3][r]));
#pragma unroll
      for (int off = 1; off <= 8; off <<= 1) mx = fmaxf(mx, __shfl_xor(mx, off));
      const float stv = st_lds[rl];
      const int qg = qbase + rl;
      const int tcol = qg * NPASS;
      float sum = 0.f, c = 0.f;
#pragma unroll
      for (int j = 0; j < 4; ++j) {
        const float s = acc[i][j][r];
        sum += __expf(s - mx);
        const int cg = n0 + wn * 64 + j * 16 + lm;
        if (s > stv && cg != tcol) c += 1.f;
      }
#pragma unroll
      for (int off = 1; off <= 8; off <<= 1) {
        sum += __shfl_xor(sum, off);
        c += __shfl_xor(c, off);
      }
      if (lm == 0) {
        pmc[qg] = mx; plc[qg] = sum; pcc[qg] = c;
      }
    }
  }
}

// ---------------------------------------------------------------------------
// Kernel 3a (stage A): merge chunks 32-at-a-time. (R18, unchanged)
// ---------------------------------------------------------------------------
__global__ __launch_bounds__(256) void merge_kernel(const float* __restrict__ pm,
                                                    const float* __restrict__ pl,
                                                    const float* __restrict__ pc,
                                                    float* __restrict__ pm2,
                                                    float* __restrict__ pl2,
                                                    float* __restrict__ pc2) {
  const int wv = threadIdx.x >> 6, lane = threadIdx.x & 63;
  const int q = (blockIdx.x & 31) * 64 + lane;
  const int slice = blockIdx.x >> 5;
  const int c0 = slice * 32 + wv * 8;
  float m = -1e30f, l = 0.f, c = 0.f;
#pragma unroll
  for (int ch = 0; ch < 8; ++ch) {
    const size_t idx = (size_t)(c0 + ch) * BQ + q;
    const float mv = pm[idx], lv = pl[idx], cv = pc[idx];
    const float nm = fmaxf(m, mv);
    l = l * __expf(m - nm) + lv * __expf(mv - nm);
    m = nm; c += cv;
  }
  __shared__ float sm[4][64], sl[4][64], sc[4][64];
  sm[wv][lane] = m; sl[wv][lane] = l; sc[wv][lane] = c;
  __syncthreads();
  if (wv == 0) {
    float M = sm[0][lane], L = sl[0][lane], C = sc[0][lane];
#pragma unroll
    for (int w = 1; w < 4; ++w) {
      const float mv = sm[w][lane];
      const float nm = fmaxf(M, mv);
      L = L * __expf(M - nm) + sl[w][lane] * __expf(mv - nm);
      M = nm; C += sc[w][lane];
    }
    const size_t o = (size_t)slice * BQ + q;
    pm2[o] = M; pl2[o] = L; pc2[o] = C;
  }
}

// ---------------------------------------------------------------------------
// Kernel 3b (stage B): merge 8 slices/query, weighted CE, mean. (R18)
// ---------------------------------------------------------------------------
__global__ __launch_bounds__(64) void finalize_kernel(const float* __restrict__ st,
                                                      const float* __restrict__ pm2,
                                                      const float* __restrict__ pl2,
                                                      const float* __restrict__ pc2,
                                                      float* __restrict__ out) {
  const int lane = threadIdx.x;
  const int q = blockIdx.x * 64 + lane;
  float m = -1e30f, l = 0.f, c = 0.f;
#pragma unroll
  for (int s = 0; s < 8; ++s) {
    const size_t idx = (size_t)s * BQ + q;
    const float mv = pm2[idx], lv = pl2[idx], cv = pc2[idx];
    const float nm = fmaxf(m, mv);
    l = l * __expf(m - nm) + lv * __expf(mv - nm);
    m = nm; c += cv;
  }
  const float raw = logf(l) + m - st[q];       // -log_softmax[target]
  const float dr = c - 1.0f;                   // rank - OPTIMAL_RANK
  const float w = 1.0f + ALPHA_C * __expf(-(dr * dr) * INV_2SIG2);
  float loss = raw * w * (1.0f / (float)BQ);
#pragma unroll
  for (int off = 32; off >= 1; off >>= 1) loss += __shfl_xor(loss, off);
  if (lane == 0) atomicAdd(out, loss);
}

// ---------------------------------------------------------------------------
extern "C" void kernel_launch(void* const* d_in, const int* in_sizes, int n_in,
                              void* d_out, int out_size, void* d_ws, size_t ws_size,
                              hipStream_t stream) {
  const float* q = (const float*)d_in[0];
  const float* p = (const float*)d_in[1];
  char* ws = (char*)d_ws;
  unsigned char* qb = (unsigned char*)ws;                  // 1,572,864 B
  float* st = (float*)(ws + 14155776);                     // 8 KB
  float* pm = (float*)(ws + 14163968);                     // 2 MB
  float* pl = (float*)(ws + 16261120);                     // 2 MB
  float* pc = (float*)(ws + 18358272);                     // 2 MB
  float* pm2 = (float*)(ws + 20455424);                    // 64 KB
  float* pl2 = (float*)(ws + 20520960);                    // 64 KB
  float* pc2 = (float*)(ws + 20586496);                    // 64 KB (end ~20.7 MB)
  float* out = (float*)d_out;

  prep_kernel<<<QCB + BQ / 4, 256, 0, stream>>>(q, p, (uint4*)qb, st, out);
  gemm_kernel<<<NBLK * MBLK, 1024, 0, stream>>>(qb, p, st, pm, pl, pc);
  merge_kernel<<<256, 256, 0, stream>>>(pm, pl, pc, pm2, pl2, pc2);
  finalize_kernel<<<BQ / 64, 64, 0, stream>>>(st, pm2, pl2, pc2, out);
}

// Round 20
// 147.115 us; speedup vs baseline: 2.3432x; 1.2392x over previous
//
#include <hip/hip_runtime.h>
#include <math.h>

// Problem: scores = q[2048x768] @ p[16384x768]^T (fp32 in), per-query
// rank-of-target + log-softmax CE + Gaussian rank weight -> mean (scalar).
// R21 = R18 VERBATIM (best measured: 146.7 us), locked in after R19/R20
// both tripped their pre-declared falsifiers:
//  - R19 (MX 32x32x64): allocator pinned VGPR=64 again -> acc spilled
//    (WRITE 488 MB, gemm 254 us). MX at this geometry closed.
//  - R20 (fused B-cast into gemm): no spill (WRITE 6.1 MB) but gemm
//    102 us > 85 falsifier: fp32 B staging quadruples staged bytes/K-tile
//    (64 KB vs 16 KB), 786K bank-conflict cyc on ds_write path, lgkmcnt(0)
//    serialization. Fused-cast closed.
// Final structure: prep (uint4 16-float cast + exact st dots) -> gemm
// (R14: fp8 16x16x32, 256x256, BK=64, triple-buffer, counted vmcnt(2),
// R13 conflict-free b128 K-permuted frag reads, R14 3-phase interleave,
// chunk-major partials) -> merge (256 blocks, 8-deep) -> finalize
// (32 blocks, 8-slice merge + weighted CE + mean).
// Session ledger: gemm structural levers exhausted (R12 +17% only win;
// R13/R14/R16 null; R17 -22%; R15/R19 spill; R20 -73%) = the documented
// 2-phase structural plateau (m233). Expected: gemm ~59-62 us (normal
// clocks), MfmaUtil ~33, FETCH ~12.4 MB, WRITE ~6.1 MB, conflicts 0,
// total ~147 us, absmax 0.5.

#define BQ 2048
#define DD 768
#define NPASS 8
#define PP 16384
#define BM 256
#define BN 256
#define BK 64
#define KITERS 12          // 768/64
#define NBLK 64            // PP/BN
#define MBLK 8             // BQ/BM
#define NCHUNKS 256        // NBLK * 4 n-waves

#define ALPHA_C 2.6f
#define INV_2SIG2 (1.0f/6.48f)   // 1/(2*1.8^2)

typedef __attribute__((ext_vector_type(4))) float floatx4;  // MFMA C/D
typedef __attribute__((ext_vector_type(2))) long longx2;    // ds_read_b128

// ---------------------------------------------------------------------------
// Kernel 1 (fused): cast q,p -> fp8 e4m3 (16 floats/thread, uint4 stores)
// + s_t exact-fp32 dots + out=0.
// ---------------------------------------------------------------------------
#define NQ16   98304     // 2048*768/16
#define NTOT16 884736    // (2048+16384)*768/16
#define NCB16  3456      // NTOT16/256
__global__ __launch_bounds__(256) void prep_kernel(const float* __restrict__ qf,
                                                   const float* __restrict__ pf,
                                                   uint4* __restrict__ qb,
                                                   uint4* __restrict__ pb,
                                                   float* __restrict__ st,
                                                   float* __restrict__ out) {
  const int b = blockIdx.x;
  if (b == 0 && threadIdx.x == 0) *out = 0.f;
  if (b < NCB16) {
    const int i = b * 256 + threadIdx.x;        // 16-float unit index
    const float4* src; uint4* dst;
    if (i < NQ16) { src = (const float4*)qf + 4 * (size_t)i; dst = qb + i; }
    else { const size_t j = (size_t)i - NQ16; src = (const float4*)pf + 4 * j; dst = pb + j; }
    const float4 v0 = src[0], v1 = src[1], v2 = src[2], v3 = src[3];
    unsigned u0 = __builtin_amdgcn_cvt_pk_fp8_f32(v0.x, v0.y, 0, 0);
    u0 = __builtin_amdgcn_cvt_pk_fp8_f32(v0.z, v0.w, u0, 1);
    unsigned u1 = __builtin_amdgcn_cvt_pk_fp8_f32(v1.x, v1.y, 0, 0);
    u1 = __builtin_amdgcn_cvt_pk_fp8_f32(v1.z, v1.w, u1, 1);
    unsigned u2 = __builtin_amdgcn_cvt_pk_fp8_f32(v2.x, v2.y, 0, 0);
    u2 = __builtin_amdgcn_cvt_pk_fp8_f32(v2.z, v2.w, u2, 1);
    unsigned u3 = __builtin_amdgcn_cvt_pk_fp8_f32(v3.x, v3.y, 0, 0);
    u3 = __builtin_amdgcn_cvt_pk_fp8_f32(v3.z, v3.w, u3, 1);
    uint4 w; w.x = u0; w.y = u1; w.z = u2; w.w = u3;
    *dst = w;
  } else {
    const int wv = threadIdx.x >> 6, lane = threadIdx.x & 63;
    const int qi = (b - NCB16) * 4 + wv;
    const float4* q4 = (const float4*)(qf + (size_t)qi * DD);
    const float4* p4 = (const float4*)(pf + (size_t)qi * NPASS * DD);
    float acc = 0.f;
#pragma unroll
    for (int u = 0; u < 3; ++u) {   // 192 float4 per row = 64 lanes * 3
      float4 a = q4[lane + 64 * u];
      float4 c = p4[lane + 64 * u];
      acc = fmaf(a.x, c.x, acc);
      acc = fmaf(a.y, c.y, acc);
      acc = fmaf(a.z, c.z, acc);
      acc = fmaf(a.w, c.w, acc);
    }
#pragma unroll
    for (int off = 32; off >= 1; off >>= 1) acc += __shfl_xor(acc, off);
    if (lane == 0) st[qi] = acc;
  }
}

// ---------------------------------------------------------------------------
// Kernel 2: fp8 MFMA GEMM 256x256, BK=64, TRIPLE-buffered global_load_lds
// with counted vmcnt (R14, best: 58.9 us, MfmaUtil 33, conflicts 0).
// 16 waves (4m x 4n), wave = 64x64 out (4x4 of 16x16x32). LDS unit = 16
// rows x 64 k-bytes = 1 KB; conflict-free b128 K-permuted frag reads
// (intra16 = lq*256+lm*16; .x -> MFMA ks=0, .y -> ks=1).
// C/D: col=lane&15, row=(lane>>4)*4+reg.
// ---------------------------------------------------------------------------
__global__ __launch_bounds__(1024) void gemm_kernel(const unsigned char* __restrict__ qb,
                                                    const unsigned char* __restrict__ pb,
                                                    const float* __restrict__ st,
                                                    float* __restrict__ pm,
                                                    float* __restrict__ pl,
                                                    float* __restrict__ pc) {
  __shared__ unsigned char As[3][16 * 1024];   // 48 KB
  __shared__ unsigned char Bs[3][16 * 1024];   // 48 KB
  __shared__ float st_lds[BM];

  const int t = threadIdx.x;
  const int lane = t & 63;
  const int wv = t >> 6;            // 0..15
  const int wm = wv >> 2, wn = wv & 3;
  const int bid = blockIdx.x;       // 0..511
  const int xcd = bid & 7;          // round-robin XCD assignment
  const int nb = xcd * 8 + ((bid >> 3) & 7);   // XCD-private pb slice (1.5 MB)
  const int mb = bid >> 6;          // 0..7
  const int qbase = mb * BM;
  const int n0 = nb * BN;
  const int lm = lane & 15;
  const int lq = lane >> 4;
  const int lds_lane = lane * 16;

  if (t < BM) st_lds[t] = st[qbase + t];

  floatx4 acc[4][4];
#pragma unroll
  for (int i = 0; i < 4; ++i)
#pragma unroll
    for (int j = 0; j < 4; ++j) acc[i][j] = (floatx4){0.f, 0.f, 0.f, 0.f};

  const size_t arow = (size_t)(qbase + wv * 16 + lm) * DD;
  const size_t brow = (size_t)(n0 + wv * 16 + lm) * DD;
  const int intra16 = lq * 256 + lm * 16;      // one 16-B chunk per lane

#define STAGE(KT, BUF)                                                          \
  {                                                                             \
    const size_t koff = (size_t)(KT) * BK + lq * 16;                            \
    __builtin_amdgcn_global_load_lds(                                           \
        (const __attribute__((address_space(1))) void*)(qb + arow + koff),      \
        (__attribute__((address_space(3))) void*)(&As[BUF][wv * 1024] + lds_lane), \
        16, 0, 0);                                                              \
    __builtin_amdgcn_global_load_lds(                                           \
        (const __attribute__((address_space(1))) void*)(pb + brow + koff),      \
        (__attribute__((address_space(3))) void*)(&Bs[BUF][wv * 1024] + lds_lane), \
        16, 0, 0);                                                              \
  }

#define MFMA8(II, JJ)                                                           \
  {                                                                             \
    acc[II][JJ]       = __builtin_amdgcn_mfma_f32_16x16x32_fp8_fp8(a2[II].x,     b2[JJ].x,     acc[II][JJ],       0, 0, 0); \
    acc[II][JJ+1]     = __builtin_amdgcn_mfma_f32_16x16x32_fp8_fp8(a2[II].x,     b2[JJ+1].x,   acc[II][JJ+1],     0, 0, 0); \
    acc[II+1][JJ]     = __builtin_amdgcn_mfma_f32_16x16x32_fp8_fp8(a2[II+1].x,   b2[JJ].x,     acc[II+1][JJ],     0, 0, 0); \
    acc[II+1][JJ+1]   = __builtin_amdgcn_mfma_f32_16x16x32_fp8_fp8(a2[II+1].x,   b2[JJ+1].x,   acc[II+1][JJ+1],   0, 0, 0); \
    acc[II][JJ]       = __builtin_amdgcn_mfma_f32_16x16x32_fp8_fp8(a2[II].y,     b2[JJ].y,     acc[II][JJ],       0, 0, 0); \
    acc[II][JJ+1]     = __builtin_amdgcn_mfma_f32_16x16x32_fp8_fp8(a2[II].y,     b2[JJ+1].y,   acc[II][JJ+1],     0, 0, 0); \
    acc[II+1][JJ]     = __builtin_amdgcn_mfma_f32_16x16x32_fp8_fp8(a2[II+1].y,   b2[JJ].y,     acc[II+1][JJ],     0, 0, 0); \
    acc[II+1][JJ+1]   = __builtin_amdgcn_mfma_f32_16x16x32_fp8_fp8(a2[II+1].y,   b2[JJ+1].y,   acc[II+1][JJ+1],   0, 0, 0); \
  }

#define COMPUTE(CB)                                                             \
  {                                                                             \
    longx2 a2[4], b2[4];                                                        \
    a2[0] = *(const longx2*)(&As[CB][(wm * 4 + 0) * 1024] + intra16);           \
    a2[1] = *(const longx2*)(&As[CB][(wm * 4 + 1) * 1024] + intra16);           \
    b2[0] = *(const longx2*)(&Bs[CB][(wn * 4 + 0) * 1024] + intra16);           \
    b2[1] = *(const longx2*)(&Bs[CB][(wn * 4 + 1) * 1024] + intra16);           \
    __builtin_amdgcn_sched_barrier(0);                                          \
    b2[2] = *(const longx2*)(&Bs[CB][(wn * 4 + 2) * 1024] + intra16);           \
    b2[3] = *(const longx2*)(&Bs[CB][(wn * 4 + 3) * 1024] + intra16);           \
    __builtin_amdgcn_sched_barrier(0);                                          \
    __builtin_amdgcn_s_setprio(1);                                              \
    MFMA8(0, 0)                                                                 \
    __builtin_amdgcn_s_setprio(0);                                              \
    __builtin_amdgcn_sched_barrier(0);                                          \
    a2[2] = *(const longx2*)(&As[CB][(wm * 4 + 2) * 1024] + intra16);           \
    a2[3] = *(const longx2*)(&As[CB][(wm * 4 + 3) * 1024] + intra16);           \
    __builtin_amdgcn_sched_barrier(0);                                          \
    __builtin_amdgcn_s_setprio(1);                                              \
    MFMA8(0, 2)                                                                 \
    __builtin_amdgcn_s_setprio(0);                                              \
    __builtin_amdgcn_sched_barrier(0);                                          \
    __builtin_amdgcn_s_setprio(1);                                              \
    MFMA8(2, 0)                                                                 \
    MFMA8(2, 2)                                                                 \
    __builtin_amdgcn_s_setprio(0);                                              \
  }

  STAGE(0, 0)
  STAGE(1, 1)
  int cur = 0;            // buffer holding K-tile kt
  int stg = 2;            // buffer to stage K-tile kt+2 into
  for (int kt = 0; kt < KITERS - 1; ++kt) {
    asm volatile("s_waitcnt vmcnt(2)" ::: "memory");
    __builtin_amdgcn_s_barrier();
    __builtin_amdgcn_sched_barrier(0);
    if (kt < KITERS - 2) STAGE(kt + 2, stg)
    COMPUTE(cur)
    cur = (cur == 2) ? 0 : cur + 1;
    stg = (stg == 2) ? 0 : stg + 1;
  }
  asm volatile("s_waitcnt vmcnt(0)" ::: "memory");
  __builtin_amdgcn_s_barrier();
  __builtin_amdgcn_sched_barrier(0);
  COMPUTE(cur)

  // ---- fused epilogue: chunk-major partials (proven R11) ----
  const int chunk = nb * 4 + wn;
  float* const pmc = pm + (size_t)chunk * BQ;
  float* const plc = pl + (size_t)chunk * BQ;
  float* const pcc = pc + (size_t)chunk * BQ;
#pragma unroll
  for (int i = 0; i < 4; ++i) {
#pragma unroll
    for (int r = 0; r < 4; ++r) {
      const int rl = wm * 64 + i * 16 + lq * 4 + r;   // local query row
      float mx = fmaxf(fmaxf(acc[i][0][r], acc[i][1][r]),
                       fmaxf(acc[i][2][r], acc[i][3][r]));
#pragma unroll
      for (int off = 1; off <= 8; off <<= 1) mx = fmaxf(mx, __shfl_xor(mx, off));
      const float stv = st_lds[rl];
      const int qg = qbase + rl;
      const int tcol = qg * NPASS;
      float sum = 0.f, c = 0.f;
#pragma unroll
      for (int j = 0; j < 4; ++j) {
        const float s = acc[i][j][r];
        sum += __expf(s - mx);
        const int cg = n0 + wn * 64 + j * 16 + lm;
        if (s > stv && cg != tcol) c += 1.f;
      }
#pragma unroll
      for (int off = 1; off <= 8; off <<= 1) {
        sum += __shfl_xor(sum, off);
        c += __shfl_xor(c, off);
      }
      if (lm == 0) {
        pmc[qg] = mx; plc[qg] = sum; pcc[qg] = c;
      }
    }
  }
}

// ---------------------------------------------------------------------------
// Kernel 3a (stage A): merge chunks 32-at-a-time. 256 blocks x 256 thr.
// Block b: queries (b&31)*64..+63, slice b>>5 (chunks slice*32..+31).
// ---------------------------------------------------------------------------
__global__ __launch_bounds__(256) void merge_kernel(const float* __restrict__ pm,
                                                    const float* __restrict__ pl,
                                                    const float* __restrict__ pc,
                                                    float* __restrict__ pm2,
                                                    float* __restrict__ pl2,
                                                    float* __restrict__ pc2) {
  const int wv = threadIdx.x >> 6, lane = threadIdx.x & 63;
  const int q = (blockIdx.x & 31) * 64 + lane;
  const int slice = blockIdx.x >> 5;
  const int c0 = slice * 32 + wv * 8;
  float m = -1e30f, l = 0.f, c = 0.f;
#pragma unroll
  for (int ch = 0; ch < 8; ++ch) {
    const size_t idx = (size_t)(c0 + ch) * BQ + q;
    const float mv = pm[idx], lv = pl[idx], cv = pc[idx];
    const float nm = fmaxf(m, mv);
    l = l * __expf(m - nm) + lv * __expf(mv - nm);
    m = nm; c += cv;
  }
  __shared__ float sm[4][64], sl[4][64], sc[4][64];
  sm[wv][lane] = m; sl[wv][lane] = l; sc[wv][lane] = c;
  __syncthreads();
  if (wv == 0) {
    float M = sm[0][lane], L = sl[0][lane], C = sc[0][lane];
#pragma unroll
    for (int w = 1; w < 4; ++w) {
      const float mv = sm[w][lane];
      const float nm = fmaxf(M, mv);
      L = L * __expf(M - nm) + sl[w][lane] * __expf(mv - nm);
      M = nm; C += sc[w][lane];
    }
    const size_t o = (size_t)slice * BQ + q;
    pm2[o] = M; pl2[o] = L; pc2[o] = C;
  }
}

// ---------------------------------------------------------------------------
// Kernel 3b (stage B): merge 8 slices/query, weighted CE, mean -> atomicAdd.
// ---------------------------------------------------------------------------
__global__ __launch_bounds__(64) void finalize_kernel(const float* __restrict__ st,
                                                      const float* __restrict__ pm2,
                                                      const float* __restrict__ pl2,
                                                      const float* __restrict__ pc2,
                                                      float* __restrict__ out) {
  const int lane = threadIdx.x;
  const int q = blockIdx.x * 64 + lane;
  float m = -1e30f, l = 0.f, c = 0.f;
#pragma unroll
  for (int s = 0; s < 8; ++s) {
    const size_t idx = (size_t)s * BQ + q;
    const float mv = pm2[idx], lv = pl2[idx], cv = pc2[idx];
    const float nm = fmaxf(m, mv);
    l = l * __expf(m - nm) + lv * __expf(mv - nm);
    m = nm; c += cv;
  }
  const float raw = logf(l) + m - st[q];       // -log_softmax[target]
  const float dr = c - 1.0f;                   // rank - OPTIMAL_RANK
  const float w = 1.0f + ALPHA_C * __expf(-(dr * dr) * INV_2SIG2);
  float loss = raw * w * (1.0f / (float)BQ);
#pragma unroll
  for (int off = 32; off >= 1; off >>= 1) loss += __shfl_xor(loss, off);
  if (lane == 0) atomicAdd(out, loss);
}

// ---------------------------------------------------------------------------
extern "C" void kernel_launch(void* const* d_in, const int* in_sizes, int n_in,
                              void* d_out, int out_size, void* d_ws, size_t ws_size,
                              hipStream_t stream) {
  const float* q = (const float*)d_in[0];
  const float* p = (const float*)d_in[1];
  char* ws = (char*)d_ws;
  unsigned char* qb = (unsigned char*)ws;                  // 1,572,864 B
  unsigned char* pb = (unsigned char*)(ws + 1572864);      // 12,582,912 B
  float* st = (float*)(ws + 14155776);                     // 8 KB
  float* pm = (float*)(ws + 14163968);                     // 2 MB
  float* pl = (float*)(ws + 16261120);                     // 2 MB
  float* pc = (float*)(ws + 18358272);                     // 2 MB
  float* pm2 = (float*)(ws + 20455424);                    // 64 KB
  float* pl2 = (float*)(ws + 20520960);                    // 64 KB
  float* pc2 = (float*)(ws + 20586496);                    // 64 KB (end ~20.7 MB)
  float* out = (float*)d_out;

  prep_kernel<<<NCB16 + BQ / 4, 256, 0, stream>>>(q, p, (uint4*)qb, (uint4*)pb, st, out);
  gemm_kernel<<<NBLK * MBLK, 1024, 0, stream>>>(qb, pb, st, pm, pl, pc);
  merge_kernel<<<256, 256, 0, stream>>>(pm, pl, pc, pm2, pl2, pc2);
  finalize_kernel<<<BQ / 64, 64, 0, stream>>>(st, pm2, pl2, pc2, out);
}